// Round 10
// baseline (403.043 us; speedup 1.0000x reference)
//
#include <hip/hip_runtime.h>
#include <math.h>

#define E_PER_B 73536
#define E_TOT   588288
#define NB 8
#define NN 384
#define NF 128
#define BLK_E 32
#define TILES_PER_BLK 24
#define K2_GRID 766            // 766*24*32 = 588288

typedef __attribute__((ext_vector_type(8)))  __bf16 bf16x8;
typedef __attribute__((ext_vector_type(16))) float  f32x16;
typedef unsigned short ushort_t;

// ---- threefry2x32, JAX partitionable scheme -> gumbel ----
__device__ __forceinline__ float gumbel_noise(unsigned l) {
  unsigned x0 = 0u;
  unsigned x1 = l;
  const unsigned ks0 = 0u, ks1 = 42u, ks2 = 0x1BD11BDAu ^ 42u;
  x0 += ks0; x1 += ks1;
#define TF_R(r) { x0 += x1; x1 = (x1 << (r)) | (x1 >> (32 - (r))); x1 ^= x0; }
  TF_R(13) TF_R(15) TF_R(26) TF_R(6)
  x0 += ks1; x1 += ks2 + 1u;
  TF_R(17) TF_R(29) TF_R(16) TF_R(24)
  x0 += ks2; x1 += ks0 + 2u;
  TF_R(13) TF_R(15) TF_R(26) TF_R(6)
  x0 += ks0; x1 += ks1 + 3u;
  TF_R(17) TF_R(29) TF_R(16) TF_R(24)
  x0 += ks1; x1 += ks2 + 4u;
  TF_R(13) TF_R(15) TF_R(26) TF_R(6)
  x0 += ks2; x1 += ks0 + 5u;
#undef TF_R
  unsigned bits = x0 ^ x1;
  float u = __uint_as_float((bits >> 9) | 0x3f800000u) - 1.0f;
  u = fmaxf(u, 1.17549435e-38f);
  float t = (float)(-log((double)u));
  return (float)(-log((double)t));
}

// ---- fp32 -> bf16 hi/mid/lo split (RNE for hi/mid, trunc lo) ----
__device__ __forceinline__ void split3(float x, ushort_t& h, ushort_t& m, ushort_t& l) {
  unsigned u = __float_as_uint(x);
  unsigned th = (u + 0x7fffu + ((u >> 16) & 1u)) & 0xffff0000u;
  float hf = __uint_as_float(th);
  float r1 = x - hf;                       // exact (Sterbenz)
  unsigned u1 = __float_as_uint(r1);
  unsigned tm = (u1 + 0x7fffu + ((u1 >> 16) & 1u)) & 0xffff0000u;
  float mf = __uint_as_float(tm);
  float r2 = r1 - mf;                      // exact
  h = (ushort_t)(th >> 16);
  m = (ushort_t)(tm >> 16);
  l = (ushort_t)(__float_as_uint(r2) >> 16);
}

// ---------------- k0: fold LN2 affine into W3 ----------------
__global__ __launch_bounds__(128) void k0_fold(
    const float* __restrict__ g2, const float* __restrict__ bt2,
    const float* __restrict__ W3, const float* __restrict__ b3,
    float* __restrict__ w3g, float* __restrict__ d2c3) {
  __shared__ double red[256];
  int f = threadIdx.x;
  w3g[f] = g2[f] * W3[f];
  red[f]       = (double)g2[f]  * (double)W3[f];
  red[128 + f] = (double)bt2[f] * (double)W3[f];
  __syncthreads();
  if (f == 0) {
    double d2 = 0.0, c3 = 0.0;
    for (int i = 0; i < 128; ++i) { d2 += red[i]; c3 += red[128 + i]; }
    d2c3[0] = (float)d2;
    d2c3[1] = (float)(c3 + (double)b3[0]);
  }
}

// ---------------- k0b: pre-split W2 into packed lane-order B-fragments ----
// Bpk[p][nc][s][l][i] bf16, p=plane(h/m/l), nc=N-strip(4), s=kstep(8),
// l=lane(64), i=reg(8). Element = split_p(W2[k][col]),
// k = s*16 + (l>>5)*8 + i, col = nc*32 + (l&31).
__global__ __launch_bounds__(256) void k0b_split(
    const float* __restrict__ W2, ushort_t* __restrict__ Bpk) {
  int t = blockIdx.x * 256 + threadIdx.x;    // 0..16383
  int k = t >> 7, col = t & 127;
  float x = W2[k * 128 + col];
  ushort_t h, m, l;
  split3(x, h, m, l);
  int nc = col >> 5;
  int ln = (col & 31) + ((k >> 3) & 1) * 32;
  int s  = k >> 4;
  int i  = k & 7;
  int base = ((nc * 8 + s) * 64 + ln) * 8 + i;
  Bpk[base]             = h;
  Bpk[16384 + base]     = m;
  Bpk[2 * 16384 + base] = l;
}

// ---------------- k1: P = nodes@W1[:128], Q = nodes@W1[128:] ----------------
__global__ __launch_bounds__(128) void k1_pq(
    const float* __restrict__ nodes, const float* __restrict__ W1,
    float* __restrict__ P, float* __restrict__ Q) {
  __shared__ float x[128];
  int row = blockIdx.x;
  int f = threadIdx.x;
  x[f] = nodes[row * 128 + f];
  __syncthreads();
  float p = 0.f, q = 0.f;
#pragma unroll 4
  for (int k = 0; k < 128; ++k) {
    float xk = x[k];
    p += xk * W1[k * 128 + f];
    q += xk * W1[(128 + k) * 128 + f];
  }
  P[row * 128 + f] = p;
  Q[row * 128 + f] = q;
}

// ---------------- k2: fused edge MLP (MFMA bf16x3) -> logits ----------------
// 766 blocks x 24 tiles of 32 edges. 256 threads (4 waves). Wave w = N-strip w.
// B fragments re-loaded per tile AFTER phase A (opaque ptr defeats LICM) so
// they are never live across phase A -> no spill. GEMM: ds_read A + MFMA only.
__global__ __launch_bounds__(256, 3) void k2_edges(
    const float* __restrict__ P, const float* __restrict__ Q,
    const float* __restrict__ b1, const float* __restrict__ g1,
    const float* __restrict__ bt1, const ushort_t* __restrict__ Bpk,
    const float* __restrict__ b2, const float* __restrict__ w3g,
    const float* __restrict__ d2c3, float* __restrict__ logits) {
  __shared__ __align__(16) unsigned char sPlanes[3 * 8192];  // h planes; epi buf aliases
  __shared__ unsigned smeta[BLK_E];
  float* sredE = (float*)sPlanes;                // [32 e][97 words] (12.4 KB)

  const int tid = threadIdx.x;
  const int w  = tid >> 6;           // wave 0..3 = N-strip
  const int l  = tid & 63;
  const unsigned lrow = (unsigned)(l & 31);
  const unsigned lk   = (unsigned)(l >> 5);
  const unsigned rb   = lrow * 256u;
  const unsigned esw  = lrow & 7u;
  const unsigned char* pl0 = sPlanes;
  const unsigned char* bp0 = (const unsigned char*)Bpk + (unsigned)(w * 8) * 1024u
                             + (unsigned)l * 16u;

  // epilogue constants (loop-invariant)
  const int col = w * 32 + (int)lrow;
  const float b2c = b2[col];
  const float w3c = w3g[col];
  const float dd2 = d2c3[0], cc3 = d2c3[1];

  bf16x8 A0h, A0m, A0l, A1h, A1m, A1l;

#define LOADA(S, ks) do {                                                     \
    const unsigned _co = (((unsigned)(2 * (ks)) + lk) ^ esw) << 4;            \
    A##S##h = *(const bf16x8*)(pl0 + rb + _co);                               \
    A##S##m = *(const bf16x8*)(pl0 + 8192 + rb + _co);                        \
    A##S##l = *(const bf16x8*)(pl0 + 2 * 8192 + rb + _co);                    \
  } while (0)

#define MFMA6(AS, ks) do {                                                    \
    __builtin_amdgcn_s_setprio(1);                                            \
    acc = __builtin_amdgcn_mfma_f32_32x32x16_bf16(A##AS##m, Bk##ks##m, acc, 0, 0, 0); \
    acc = __builtin_amdgcn_mfma_f32_32x32x16_bf16(A##AS##l, Bk##ks##h, acc, 0, 0, 0); \
    acc = __builtin_amdgcn_mfma_f32_32x32x16_bf16(A##AS##h, Bk##ks##l, acc, 0, 0, 0); \
    acc = __builtin_amdgcn_mfma_f32_32x32x16_bf16(A##AS##m, Bk##ks##h, acc, 0, 0, 0); \
    acc = __builtin_amdgcn_mfma_f32_32x32x16_bf16(A##AS##h, Bk##ks##m, acc, 0, 0, 0); \
    acc = __builtin_amdgcn_mfma_f32_32x32x16_bf16(A##AS##h, Bk##ks##h, acc, 0, 0, 0); \
    __builtin_amdgcn_s_setprio(0);                                            \
    __builtin_amdgcn_sched_barrier(0);                                        \
  } while (0)

  for (int it = 0; it < TILES_PER_BLK; ++it) {
    const int tile = blockIdx.x * TILES_PER_BLK + it;

    // =============== phase A: h1 = LN1(relu(P[si]+Q[so]+b1)) ================
    {
      const int e = tid >> 3;        // edge 0..31
      const int q = tid & 7;         // 16-elem chunk
      int g = tile * BLK_E + e;
      int b = g / E_PER_B;
      int t0 = g - b * E_PER_B;
      int si = (int)((1.0 + sqrt(1.0 + 8.0 * (double)t0)) * 0.5);
      while (si * (si - 1) / 2 > t0) --si;
      while ((si + 1) * si / 2 <= t0) ++si;
      int so = t0 - si * (si - 1) / 2;
      if (q == 0) smeta[e] = (unsigned)((b * NN + si) * (NN - 1) + so);

      const float4* P4  = (const float4*)(P + (size_t)(b * NN + si) * 128) + q * 4;
      const float4* Q4  = (const float4*)(Q + (size_t)(b * NN + so) * 128) + q * 4;
      const float4* B14 = (const float4*)b1 + q * 4;
      float av[16];
      float sum = 0.f;
#pragma unroll
      for (int k4 = 0; k4 < 4; ++k4) {
        float4 p = P4[k4], qq = Q4[k4], bb = B14[k4];
        float v0 = fmaxf(p.x + qq.x + bb.x, 0.f);
        float v1 = fmaxf(p.y + qq.y + bb.y, 0.f);
        float v2 = fmaxf(p.z + qq.z + bb.z, 0.f);
        float v3 = fmaxf(p.w + qq.w + bb.w, 0.f);
        av[4 * k4 + 0] = v0; av[4 * k4 + 1] = v1;
        av[4 * k4 + 2] = v2; av[4 * k4 + 3] = v3;
        sum += v0 + v1 + v2 + v3;
      }
      sum += __shfl_xor(sum, 1);
      sum += __shfl_xor(sum, 2);
      sum += __shfl_xor(sum, 4);
      float m = sum * 0.0078125f;
      float ss = 0.f;
#pragma unroll
      for (int j = 0; j < 16; ++j) { float dx = av[j] - m; ss += dx * dx; }
      ss += __shfl_xor(ss, 1);
      ss += __shfl_xor(ss, 2);
      ss += __shfl_xor(ss, 4);
      float var = ss * 0.0078125f;
      float rs = 1.0f / sqrtf(var + 1e-5f);

      const float4* G14  = (const float4*)g1 + q * 4;
      const float4* BT14 = (const float4*)bt1 + q * 4;
#pragma unroll
      for (int k4 = 0; k4 < 4; ++k4) {
        float4 gg = G14[k4], bt = BT14[k4];
        av[4 * k4 + 0] = (av[4 * k4 + 0] - m) * rs * gg.x + bt.x;
        av[4 * k4 + 1] = (av[4 * k4 + 1] - m) * rs * gg.y + bt.y;
        av[4 * k4 + 2] = (av[4 * k4 + 2] - m) * rs * gg.z + bt.z;
        av[4 * k4 + 3] = (av[4 * k4 + 3] - m) * rs * gg.w + bt.w;
      }
      const unsigned esw0 = (unsigned)(e & 7);
#pragma unroll
      for (int j = 0; j < 2; ++j) {
        unsigned ph[4], pm[4], pl[4];
#pragma unroll
        for (int ii = 0; ii < 4; ++ii) {
          ushort_t h0, m0, l0, h1x, m1x, l1x;
          split3(av[j * 8 + 2 * ii],     h0, m0, l0);
          split3(av[j * 8 + 2 * ii + 1], h1x, m1x, l1x);
          ph[ii] = (unsigned)h0 | ((unsigned)h1x << 16);
          pm[ii] = (unsigned)m0 | ((unsigned)m1x << 16);
          pl[ii] = (unsigned)l0 | ((unsigned)l1x << 16);
        }
        unsigned slot = (unsigned)(2 * q + j) ^ esw0;
        unsigned base = (unsigned)e * 256u + (slot << 4);
        *(uint4*)(sPlanes + base)             = make_uint4(ph[0], ph[1], ph[2], ph[3]);
        *(uint4*)(sPlanes + 8192 + base)      = make_uint4(pm[0], pm[1], pm[2], pm[3]);
        *(uint4*)(sPlanes + 2 * 8192 + base)  = make_uint4(pl[0], pl[1], pl[2], pl[3]);
      }
    }

    // ---- B fragments for this wave's strip: re-loaded EVERY tile.
    // Opaque pointer defeats LICM so they are never live across phase A.
    const unsigned char* bpt = bp0;
    asm volatile("" : "+v"(bpt));
#define LOADBK(ks)                                                            \
    bf16x8 Bk##ks##h = *(const bf16x8*)(bpt + (ks) * 1024u);                  \
    bf16x8 Bk##ks##m = *(const bf16x8*)(bpt + 32768u + (ks) * 1024u);         \
    bf16x8 Bk##ks##l = *(const bf16x8*)(bpt + 65536u + (ks) * 1024u);
    LOADBK(0) LOADBK(1) LOADBK(2) LOADBK(3)
    LOADBK(4) LOADBK(5) LOADBK(6) LOADBK(7)
#undef LOADBK

    __syncthreads();

    // ===== GEMM: h1[32x128] @ W2strip[128x32], 6-product bf16, LDS-only =====
    f32x16 acc;
#pragma unroll
    for (int i = 0; i < 16; ++i) acc[i] = 0.f;

    LOADA(0, 0);
    LOADA(1, 1); MFMA6(0, 0);
    LOADA(0, 2); MFMA6(1, 1);
    LOADA(1, 3); MFMA6(0, 2);
    LOADA(0, 4); MFMA6(1, 3);
    LOADA(1, 5); MFMA6(0, 4);
    LOADA(0, 6); MFMA6(1, 5);
    LOADA(1, 7); MFMA6(0, 6);
    MFMA6(1, 7);
    __syncthreads();   // A reads done; planes reusable as sredE

    // =============== epilogue: per-edge stats partials ======================
    {
      const unsigned ebase = 4u * lk;
#pragma unroll
      for (int r = 0; r < 16; ++r) {
        float a = acc[r];
        float rr = fmaxf(a + b2c, 0.f);
        float s_ = rr, q_ = rr * rr, d_ = rr * w3c;
        s_ += __shfl_xor(s_, 1); s_ += __shfl_xor(s_, 2);
        q_ += __shfl_xor(q_, 1); q_ += __shfl_xor(q_, 2);
        d_ += __shfl_xor(d_, 1); d_ += __shfl_xor(d_, 2);
        if ((l & 3) == 0) {
          unsigned e = ebase + (unsigned)((r & 3) + 8 * (r >> 2));
          unsigned idx = e * 97u + (unsigned)(w * 8 + (int)(lrow >> 2)) * 3u;
          sredE[idx]     = s_;
          sredE[idx + 1] = q_;
          sredE[idx + 2] = d_;
        }
      }
    }
    __syncthreads();

    // =============== pass 2: LN2-fold + W3 -> logit =========================
    if (tid < BLK_E) {
      const float* rp = sredE + tid * 97;
      float s = 0.f, q = 0.f, d = 0.f;
#pragma unroll
      for (int j = 0; j < 32; ++j) {
        s += rp[3 * j];
        q += rp[3 * j + 1];
        d += rp[3 * j + 2];
      }
      float m2 = s * 0.0078125f;
      float var = fmaxf(q * 0.0078125f - m2 * m2, 0.f);
      float rs2 = 1.0f / sqrtf(var + 1e-5f);
      logits[smeta[tid]] = rs2 * d - m2 * rs2 * dd2 + cc3;
    }
    __syncthreads();   // smeta/sredE free before next tile's phase A
  }
#undef LOADA
#undef MFMA6
}

// ---------------- kz: zero output ----------------
__global__ __launch_bounds__(256) void kz_zero(float4* __restrict__ out, int n4) {
  int i = blockIdx.x * 256 + threadIdx.x;
  if (i < n4) out[i] = make_float4(0.f, 0.f, 0.f, 0.f);
}

// ---------------- k3: per (b,i,sample) gumbel argmax -> out=1 ----------------
__global__ __launch_bounds__(320) void k3_argmax(
    const float* __restrict__ logits, float* __restrict__ out) {
  int blk = blockIdx.x;
  int b = blk / NN;
  int i = blk - b * NN;
  if (i == 0) return;                    // row 0's pick lands on the diagonal
  int s = threadIdx.x >> 6;              // sample 0..4 (one wave each)
  int lane = threadIdx.x & 63;
  const float* row = logits + (size_t)(b * NN + i) * (NN - 1);
  float best = -INFINITY;
  int bestj = 0x7fffffff;
  unsigned lbase = ((unsigned)((s * NB + b) * NN + i)) * (NN - 1);
  for (int j = lane; j < i; j += 64) {
    float v = row[j] + gumbel_noise(lbase + (unsigned)j);
    if (v > best) { best = v; bestj = j; }
  }
  for (int off = 32; off; off >>= 1) {
    float ov = __shfl_down(best, off);
    int oj = __shfl_down(bestj, off);
    if (ov > best || (ov == best && oj < bestj)) { best = ov; bestj = oj; }
  }
  if (lane == 0) out[((size_t)(b * NN) + i) * NN + bestj] = 1.0f;
}

// ---------------- launch ----------------
extern "C" void kernel_launch(void* const* d_in, const int* in_sizes, int n_in,
                              void* d_out, int out_size, void* d_ws, size_t ws_size,
                              hipStream_t stream) {
  const float* nodes = (const float*)d_in[0];
  const float* W1  = (const float*)d_in[1];
  const float* b1  = (const float*)d_in[2];
  const float* g1  = (const float*)d_in[3];
  const float* bt1 = (const float*)d_in[4];
  const float* W2  = (const float*)d_in[5];
  const float* b2  = (const float*)d_in[6];
  const float* g2  = (const float*)d_in[7];
  const float* bt2 = (const float*)d_in[8];
  const float* W3  = (const float*)d_in[9];
  const float* b3  = (const float*)d_in[10];

  float* ws     = (float*)d_ws;
  float* Pw     = ws;                 // 393216 floats
  float* Qw     = ws + 393216;        // 393216
  float* w3g    = ws + 786432;        // 128
  float* d2c3   = ws + 786560;        // 2
  float* logits = ws + 786688;        // 1176576
  ushort_t* Bpk = (ushort_t*)(ws + 1963264);  // 49152 bf16 = 96 KB

  hipLaunchKernelGGL(k0_fold, dim3(1), dim3(128), 0, stream, g2, bt2, W3, b3, w3g, d2c3);
  hipLaunchKernelGGL(k0b_split, dim3(64), dim3(256), 0, stream, W2, Bpk);
  hipLaunchKernelGGL(k1_pq, dim3(NB * NN), dim3(128), 0, stream, nodes, W1, Pw, Qw);
  hipLaunchKernelGGL(k2_edges, dim3(K2_GRID), dim3(256), 0, stream,
                     Pw, Qw, b1, g1, bt1, Bpk, b2, w3g, d2c3, logits);
  int n4 = out_size / 4;              // 294912
  hipLaunchKernelGGL(kz_zero, dim3((n4 + 255) / 256), dim3(256), 0, stream,
                     (float4*)d_out, n4);
  hipLaunchKernelGGL(k3_argmax, dim3(NB * NN), dim3(320), 0, stream, logits, (float*)d_out);
}

// Round 11
// 332.868 us; speedup vs baseline: 1.2108x; 1.2108x over previous
//
#include <hip/hip_runtime.h>
#include <math.h>

#define E_PER_B 73536
#define E_TOT   588288
#define NB 8
#define NN 384
#define NF 128
#define BLK_E 32
#define TILES_PER_BLK 24
#define K2_GRID 766            // 766*24*32 = 588288

typedef __attribute__((ext_vector_type(8)))  __bf16 bf16x8;
typedef __attribute__((ext_vector_type(16))) float  f32x16;
typedef unsigned short ushort_t;

// ---- threefry2x32, JAX partitionable scheme -> gumbel ----
__device__ __forceinline__ float gumbel_noise(unsigned l) {
  unsigned x0 = 0u;
  unsigned x1 = l;
  const unsigned ks0 = 0u, ks1 = 42u, ks2 = 0x1BD11BDAu ^ 42u;
  x0 += ks0; x1 += ks1;
#define TF_R(r) { x0 += x1; x1 = (x1 << (r)) | (x1 >> (32 - (r))); x1 ^= x0; }
  TF_R(13) TF_R(15) TF_R(26) TF_R(6)
  x0 += ks1; x1 += ks2 + 1u;
  TF_R(17) TF_R(29) TF_R(16) TF_R(24)
  x0 += ks2; x1 += ks0 + 2u;
  TF_R(13) TF_R(15) TF_R(26) TF_R(6)
  x0 += ks0; x1 += ks1 + 3u;
  TF_R(17) TF_R(29) TF_R(16) TF_R(24)
  x0 += ks1; x1 += ks2 + 4u;
  TF_R(13) TF_R(15) TF_R(26) TF_R(6)
  x0 += ks2; x1 += ks0 + 5u;
#undef TF_R
  unsigned bits = x0 ^ x1;
  float u = __uint_as_float((bits >> 9) | 0x3f800000u) - 1.0f;
  u = fmaxf(u, 1.17549435e-38f);
  float t = (float)(-log((double)u));
  return (float)(-log((double)t));
}

// ---- fp32 -> bf16 hi/mid/lo split (RNE for hi/mid, trunc lo) ----
__device__ __forceinline__ void split3(float x, ushort_t& h, ushort_t& m, ushort_t& l) {
  unsigned u = __float_as_uint(x);
  unsigned th = (u + 0x7fffu + ((u >> 16) & 1u)) & 0xffff0000u;
  float hf = __uint_as_float(th);
  float r1 = x - hf;                       // exact (Sterbenz)
  unsigned u1 = __float_as_uint(r1);
  unsigned tm = (u1 + 0x7fffu + ((u1 >> 16) & 1u)) & 0xffff0000u;
  float mf = __uint_as_float(tm);
  float r2 = r1 - mf;                      // exact
  h = (ushort_t)(th >> 16);
  m = (ushort_t)(tm >> 16);
  l = (ushort_t)(__float_as_uint(r2) >> 16);
}

// ---------------- k0: fold LN2 affine into W3 ----------------
__global__ __launch_bounds__(128) void k0_fold(
    const float* __restrict__ g2, const float* __restrict__ bt2,
    const float* __restrict__ W3, const float* __restrict__ b3,
    float* __restrict__ w3g, float* __restrict__ d2c3) {
  __shared__ double red[256];
  int f = threadIdx.x;
  w3g[f] = g2[f] * W3[f];
  red[f]       = (double)g2[f]  * (double)W3[f];
  red[128 + f] = (double)bt2[f] * (double)W3[f];
  __syncthreads();
  if (f == 0) {
    double d2 = 0.0, c3 = 0.0;
    for (int i = 0; i < 128; ++i) { d2 += red[i]; c3 += red[128 + i]; }
    d2c3[0] = (float)d2;
    d2c3[1] = (float)(c3 + (double)b3[0]);
  }
}

// ---------------- k0b: pre-split W2 into packed lane-order B-fragments ----
// Bpk[p][nc][s][l][i] bf16, p=plane(h/m/l), nc=N-strip(4), s=kstep(8),
// l=lane(64), i=reg(8). Element = split_p(W2[k][col]),
// k = s*16 + (l>>5)*8 + i, col = nc*32 + (l&31).
__global__ __launch_bounds__(256) void k0b_split(
    const float* __restrict__ W2, ushort_t* __restrict__ Bpk) {
  int t = blockIdx.x * 256 + threadIdx.x;    // 0..16383
  int k = t >> 7, col = t & 127;
  float x = W2[k * 128 + col];
  ushort_t h, m, l;
  split3(x, h, m, l);
  int nc = col >> 5;
  int ln = (col & 31) + ((k >> 3) & 1) * 32;
  int s  = k >> 4;
  int i  = k & 7;
  int base = ((nc * 8 + s) * 64 + ln) * 8 + i;
  Bpk[base]             = h;
  Bpk[16384 + base]     = m;
  Bpk[2 * 16384 + base] = l;
}

// ---------------- k1: P = nodes@W1[:128], Q = nodes@W1[128:] ----------------
__global__ __launch_bounds__(128) void k1_pq(
    const float* __restrict__ nodes, const float* __restrict__ W1,
    float* __restrict__ P, float* __restrict__ Q) {
  __shared__ float x[128];
  int row = blockIdx.x;
  int f = threadIdx.x;
  x[f] = nodes[row * 128 + f];
  __syncthreads();
  float p = 0.f, q = 0.f;
#pragma unroll 4
  for (int k = 0; k < 128; ++k) {
    float xk = x[k];
    p += xk * W1[k * 128 + f];
    q += xk * W1[(128 + k) * 128 + f];
  }
  P[row * 128 + f] = p;
  Q[row * 128 + f] = q;
}

// ---------------- k2: fused edge MLP (MFMA bf16x3) -> logits ----------------
// 766 blocks x 24 tiles of 32 edges. 256 threads (4 waves). Wave w = N-strip w.
// amdgpu_waves_per_eu(3,3) pins the allocator to a firm 168-VGPR budget
// (default heuristic targets 6 waves/EU = 84 regs and spills, R6-R10).
// B loads staggered in two halves to cap peak B-liveness at ~72 regs.
__global__ __launch_bounds__(256)
__attribute__((amdgpu_waves_per_eu(3, 3)))
void k2_edges(
    const float* __restrict__ P, const float* __restrict__ Q,
    const float* __restrict__ b1, const float* __restrict__ g1,
    const float* __restrict__ bt1, const ushort_t* __restrict__ Bpk,
    const float* __restrict__ b2, const float* __restrict__ w3g,
    const float* __restrict__ d2c3, float* __restrict__ logits) {
  __shared__ __align__(16) unsigned char sPlanes[3 * 8192];  // h planes; epi buf aliases
  __shared__ unsigned smeta[BLK_E];
  float* sredE = (float*)sPlanes;                // [32 e][97 words] (12.4 KB)

  const int tid = threadIdx.x;
  const int w  = tid >> 6;           // wave 0..3 = N-strip
  const int l  = tid & 63;
  const unsigned lrow = (unsigned)(l & 31);
  const unsigned lk   = (unsigned)(l >> 5);
  const unsigned rb   = lrow * 256u;
  const unsigned esw  = lrow & 7u;
  const unsigned char* pl0 = sPlanes;
  const unsigned char* bp0 = (const unsigned char*)Bpk + (unsigned)(w * 8) * 1024u
                             + (unsigned)l * 16u;

  // epilogue constants (loop-invariant)
  const int col = w * 32 + (int)lrow;
  const float b2c = b2[col];
  const float w3c = w3g[col];
  const float dd2 = d2c3[0], cc3 = d2c3[1];

  bf16x8 A0h, A0m, A0l, A1h, A1m, A1l;

#define LOADA(S, ks) do {                                                     \
    const unsigned _co = (((unsigned)(2 * (ks)) + lk) ^ esw) << 4;            \
    A##S##h = *(const bf16x8*)(pl0 + rb + _co);                               \
    A##S##m = *(const bf16x8*)(pl0 + 8192 + rb + _co);                        \
    A##S##l = *(const bf16x8*)(pl0 + 2 * 8192 + rb + _co);                    \
  } while (0)

#define MFMA6(AS, ks) do {                                                    \
    __builtin_amdgcn_s_setprio(1);                                            \
    acc = __builtin_amdgcn_mfma_f32_32x32x16_bf16(A##AS##m, Bk##ks##m, acc, 0, 0, 0); \
    acc = __builtin_amdgcn_mfma_f32_32x32x16_bf16(A##AS##l, Bk##ks##h, acc, 0, 0, 0); \
    acc = __builtin_amdgcn_mfma_f32_32x32x16_bf16(A##AS##h, Bk##ks##l, acc, 0, 0, 0); \
    acc = __builtin_amdgcn_mfma_f32_32x32x16_bf16(A##AS##m, Bk##ks##h, acc, 0, 0, 0); \
    acc = __builtin_amdgcn_mfma_f32_32x32x16_bf16(A##AS##h, Bk##ks##m, acc, 0, 0, 0); \
    acc = __builtin_amdgcn_mfma_f32_32x32x16_bf16(A##AS##h, Bk##ks##h, acc, 0, 0, 0); \
    __builtin_amdgcn_s_setprio(0);                                            \
    __builtin_amdgcn_sched_barrier(0);                                        \
  } while (0)

#define LOADBK(ks)                                                            \
    bf16x8 Bk##ks##h = *(const bf16x8*)(bpt + (ks) * 1024u);                  \
    bf16x8 Bk##ks##m = *(const bf16x8*)(bpt + 32768u + (ks) * 1024u);         \
    bf16x8 Bk##ks##l = *(const bf16x8*)(bpt + 65536u + (ks) * 1024u);

  for (int it = 0; it < TILES_PER_BLK; ++it) {
    const int tile = blockIdx.x * TILES_PER_BLK + it;

    // =============== phase A: h1 = LN1(relu(P[si]+Q[so]+b1)) ================
    {
      const int e = tid >> 3;        // edge 0..31
      const int q = tid & 7;         // 16-elem chunk
      int g = tile * BLK_E + e;
      int b = g / E_PER_B;
      int t0 = g - b * E_PER_B;
      int si = (int)((1.0 + sqrt(1.0 + 8.0 * (double)t0)) * 0.5);
      while (si * (si - 1) / 2 > t0) --si;
      while ((si + 1) * si / 2 <= t0) ++si;
      int so = t0 - si * (si - 1) / 2;
      if (q == 0) smeta[e] = (unsigned)((b * NN + si) * (NN - 1) + so);

      const float4* P4  = (const float4*)(P + (size_t)(b * NN + si) * 128) + q * 4;
      const float4* Q4  = (const float4*)(Q + (size_t)(b * NN + so) * 128) + q * 4;
      const float4* B14 = (const float4*)b1 + q * 4;
      float av[16];
      float sum = 0.f;
#pragma unroll
      for (int k4 = 0; k4 < 4; ++k4) {
        float4 p = P4[k4], qq = Q4[k4], bb = B14[k4];
        float v0 = fmaxf(p.x + qq.x + bb.x, 0.f);
        float v1 = fmaxf(p.y + qq.y + bb.y, 0.f);
        float v2 = fmaxf(p.z + qq.z + bb.z, 0.f);
        float v3 = fmaxf(p.w + qq.w + bb.w, 0.f);
        av[4 * k4 + 0] = v0; av[4 * k4 + 1] = v1;
        av[4 * k4 + 2] = v2; av[4 * k4 + 3] = v3;
        sum += v0 + v1 + v2 + v3;
      }
      sum += __shfl_xor(sum, 1);
      sum += __shfl_xor(sum, 2);
      sum += __shfl_xor(sum, 4);
      float m = sum * 0.0078125f;
      float ss = 0.f;
#pragma unroll
      for (int j = 0; j < 16; ++j) { float dx = av[j] - m; ss += dx * dx; }
      ss += __shfl_xor(ss, 1);
      ss += __shfl_xor(ss, 2);
      ss += __shfl_xor(ss, 4);
      float var = ss * 0.0078125f;
      float rs = 1.0f / sqrtf(var + 1e-5f);

      const float4* G14  = (const float4*)g1 + q * 4;
      const float4* BT14 = (const float4*)bt1 + q * 4;
#pragma unroll
      for (int k4 = 0; k4 < 4; ++k4) {
        float4 gg = G14[k4], bt = BT14[k4];
        av[4 * k4 + 0] = (av[4 * k4 + 0] - m) * rs * gg.x + bt.x;
        av[4 * k4 + 1] = (av[4 * k4 + 1] - m) * rs * gg.y + bt.y;
        av[4 * k4 + 2] = (av[4 * k4 + 2] - m) * rs * gg.z + bt.z;
        av[4 * k4 + 3] = (av[4 * k4 + 3] - m) * rs * gg.w + bt.w;
      }
      const unsigned esw0 = (unsigned)(e & 7);
#pragma unroll
      for (int j = 0; j < 2; ++j) {
        unsigned ph[4], pm[4], pl[4];
#pragma unroll
        for (int ii = 0; ii < 4; ++ii) {
          ushort_t h0, m0, l0, h1x, m1x, l1x;
          split3(av[j * 8 + 2 * ii],     h0, m0, l0);
          split3(av[j * 8 + 2 * ii + 1], h1x, m1x, l1x);
          ph[ii] = (unsigned)h0 | ((unsigned)h1x << 16);
          pm[ii] = (unsigned)m0 | ((unsigned)m1x << 16);
          pl[ii] = (unsigned)l0 | ((unsigned)l1x << 16);
        }
        unsigned slot = (unsigned)(2 * q + j) ^ esw0;
        unsigned base = (unsigned)e * 256u + (slot << 4);
        *(uint4*)(sPlanes + base)             = make_uint4(ph[0], ph[1], ph[2], ph[3]);
        *(uint4*)(sPlanes + 8192 + base)      = make_uint4(pm[0], pm[1], pm[2], pm[3]);
        *(uint4*)(sPlanes + 2 * 8192 + base)  = make_uint4(pl[0], pl[1], pl[2], pl[3]);
      }
    }

    // ---- B half 1 (ksteps 0-3): issued before the barrier, never live
    // across phase A. Opaque pointer defeats LICM across tiles.
    const unsigned char* bpt = bp0;
    asm volatile("" : "+v"(bpt));
    LOADBK(0) LOADBK(1) LOADBK(2) LOADBK(3)

    __syncthreads();

    // ===== GEMM: h1[32x128] @ W2strip[128x32], 6-product bf16 ==============
    f32x16 acc;
#pragma unroll
    for (int i = 0; i < 16; ++i) acc[i] = 0.f;

    LOADA(0, 0);
    LOADA(1, 1); MFMA6(0, 0);
    LOADA(0, 2); MFMA6(1, 1);
    // ---- B half 2 (ksteps 4-7): Bk0/Bk1 are dead; consumed 2+ clusters later
    LOADBK(4) LOADBK(5) LOADBK(6) LOADBK(7)
    LOADA(1, 3); MFMA6(0, 2);
    LOADA(0, 4); MFMA6(1, 3);
    LOADA(1, 5); MFMA6(0, 4);
    LOADA(0, 6); MFMA6(1, 5);
    LOADA(1, 7); MFMA6(0, 6);
    MFMA6(1, 7);
    __syncthreads();   // A reads done; planes reusable as sredE

    // =============== epilogue: per-edge stats partials ======================
    {
      const unsigned ebase = 4u * lk;
#pragma unroll
      for (int r = 0; r < 16; ++r) {
        float a = acc[r];
        float rr = fmaxf(a + b2c, 0.f);
        float s_ = rr, q_ = rr * rr, d_ = rr * w3c;
        s_ += __shfl_xor(s_, 1); s_ += __shfl_xor(s_, 2);
        q_ += __shfl_xor(q_, 1); q_ += __shfl_xor(q_, 2);
        d_ += __shfl_xor(d_, 1); d_ += __shfl_xor(d_, 2);
        if ((l & 3) == 0) {
          unsigned e = ebase + (unsigned)((r & 3) + 8 * (r >> 2));
          unsigned idx = e * 97u + (unsigned)(w * 8 + (int)(lrow >> 2)) * 3u;
          sredE[idx]     = s_;
          sredE[idx + 1] = q_;
          sredE[idx + 2] = d_;
        }
      }
    }
    __syncthreads();

    // =============== pass 2: LN2-fold + W3 -> logit =========================
    if (tid < BLK_E) {
      const float* rp = sredE + tid * 97;
      float s = 0.f, q = 0.f, d = 0.f;
#pragma unroll
      for (int j = 0; j < 32; ++j) {
        s += rp[3 * j];
        q += rp[3 * j + 1];
        d += rp[3 * j + 2];
      }
      float m2 = s * 0.0078125f;
      float var = fmaxf(q * 0.0078125f - m2 * m2, 0.f);
      float rs2 = 1.0f / sqrtf(var + 1e-5f);
      logits[smeta[tid]] = rs2 * d - m2 * rs2 * dd2 + cc3;
    }
    __syncthreads();   // smeta/sredE free before next tile's phase A
  }
#undef LOADA
#undef MFMA6
#undef LOADBK
}

// ---------------- kz: zero output ----------------
__global__ __launch_bounds__(256) void kz_zero(float4* __restrict__ out, int n4) {
  int i = blockIdx.x * 256 + threadIdx.x;
  if (i < n4) out[i] = make_float4(0.f, 0.f, 0.f, 0.f);
}

// ---------------- k3: per (b,i,sample) gumbel argmax -> out=1 ----------------
__global__ __launch_bounds__(320) void k3_argmax(
    const float* __restrict__ logits, float* __restrict__ out) {
  int blk = blockIdx.x;
  int b = blk / NN;
  int i = blk - b * NN;
  if (i == 0) return;                    // row 0's pick lands on the diagonal
  int s = threadIdx.x >> 6;              // sample 0..4 (one wave each)
  int lane = threadIdx.x & 63;
  const float* row = logits + (size_t)(b * NN + i) * (NN - 1);
  float best = -INFINITY;
  int bestj = 0x7fffffff;
  unsigned lbase = ((unsigned)((s * NB + b) * NN + i)) * (NN - 1);
  for (int j = lane; j < i; j += 64) {
    float v = row[j] + gumbel_noise(lbase + (unsigned)j);
    if (v > best) { best = v; bestj = j; }
  }
  for (int off = 32; off; off >>= 1) {
    float ov = __shfl_down(best, off);
    int oj = __shfl_down(bestj, off);
    if (ov > best || (ov == best && oj < bestj)) { best = ov; bestj = oj; }
  }
  if (lane == 0) out[((size_t)(b * NN) + i) * NN + bestj] = 1.0f;
}

// ---------------- launch ----------------
extern "C" void kernel_launch(void* const* d_in, const int* in_sizes, int n_in,
                              void* d_out, int out_size, void* d_ws, size_t ws_size,
                              hipStream_t stream) {
  const float* nodes = (const float*)d_in[0];
  const float* W1  = (const float*)d_in[1];
  const float* b1  = (const float*)d_in[2];
  const float* g1  = (const float*)d_in[3];
  const float* bt1 = (const float*)d_in[4];
  const float* W2  = (const float*)d_in[5];
  const float* b2  = (const float*)d_in[6];
  const float* g2  = (const float*)d_in[7];
  const float* bt2 = (const float*)d_in[8];
  const float* W3  = (const float*)d_in[9];
  const float* b3  = (const float*)d_in[10];

  float* ws     = (float*)d_ws;
  float* Pw     = ws;                 // 393216 floats
  float* Qw     = ws + 393216;        // 393216
  float* w3g    = ws + 786432;        // 128
  float* d2c3   = ws + 786560;        // 2
  float* logits = ws + 786688;        // 1176576
  ushort_t* Bpk = (ushort_t*)(ws + 1963264);  // 49152 bf16 = 96 KB

  hipLaunchKernelGGL(k0_fold, dim3(1), dim3(128), 0, stream, g2, bt2, W3, b3, w3g, d2c3);
  hipLaunchKernelGGL(k0b_split, dim3(64), dim3(256), 0, stream, W2, Bpk);
  hipLaunchKernelGGL(k1_pq, dim3(NB * NN), dim3(128), 0, stream, nodes, W1, Pw, Qw);
  hipLaunchKernelGGL(k2_edges, dim3(K2_GRID), dim3(256), 0, stream,
                     Pw, Qw, b1, g1, bt1, Bpk, b2, w3g, d2c3, logits);
  int n4 = out_size / 4;              // 294912
  hipLaunchKernelGGL(kz_zero, dim3((n4 + 255) / 256), dim3(256), 0, stream,
                     (float4*)d_out, n4);
  hipLaunchKernelGGL(k3_argmax, dim3(NB * NN), dim3(320), 0, stream, logits, (float*)d_out);
}

// Round 12
// 270.407 us; speedup vs baseline: 1.4905x; 1.2310x over previous
//
#include <hip/hip_runtime.h>
#include <math.h>

#define E_PER_B 73536
#define E_TOT   588288
#define NB 8
#define NN 384
#define NF 128
#define BLK_E 32
#define TILES_PER_BLK 4
#define K2_GRID 4596           // 4596*4*32 = 588288

typedef __attribute__((ext_vector_type(8)))  __bf16 bf16x8;
typedef __attribute__((ext_vector_type(16))) float  f32x16;
typedef unsigned short ushort_t;

// ---- threefry2x32, JAX partitionable scheme -> gumbel ----
__device__ __forceinline__ float gumbel_noise(unsigned l) {
  unsigned x0 = 0u;
  unsigned x1 = l;
  const unsigned ks0 = 0u, ks1 = 42u, ks2 = 0x1BD11BDAu ^ 42u;
  x0 += ks0; x1 += ks1;
#define TF_R(r) { x0 += x1; x1 = (x1 << (r)) | (x1 >> (32 - (r))); x1 ^= x0; }
  TF_R(13) TF_R(15) TF_R(26) TF_R(6)
  x0 += ks1; x1 += ks2 + 1u;
  TF_R(17) TF_R(29) TF_R(16) TF_R(24)
  x0 += ks2; x1 += ks0 + 2u;
  TF_R(13) TF_R(15) TF_R(26) TF_R(6)
  x0 += ks0; x1 += ks1 + 3u;
  TF_R(17) TF_R(29) TF_R(16) TF_R(24)
  x0 += ks1; x1 += ks2 + 4u;
  TF_R(13) TF_R(15) TF_R(26) TF_R(6)
  x0 += ks2; x1 += ks0 + 5u;
#undef TF_R
  unsigned bits = x0 ^ x1;
  float u = __uint_as_float((bits >> 9) | 0x3f800000u) - 1.0f;
  u = fmaxf(u, 1.17549435e-38f);
  float t = (float)(-log((double)u));
  return (float)(-log((double)t));
}

// ---- fp32 -> bf16 hi/mid/lo split (RNE for hi/mid, trunc lo) ----
__device__ __forceinline__ void split3(float x, ushort_t& h, ushort_t& m, ushort_t& l) {
  unsigned u = __float_as_uint(x);
  unsigned th = (u + 0x7fffu + ((u >> 16) & 1u)) & 0xffff0000u;
  float hf = __uint_as_float(th);
  float r1 = x - hf;                       // exact (Sterbenz)
  unsigned u1 = __float_as_uint(r1);
  unsigned tm = (u1 + 0x7fffu + ((u1 >> 16) & 1u)) & 0xffff0000u;
  float mf = __uint_as_float(tm);
  float r2 = r1 - mf;                      // exact
  h = (ushort_t)(th >> 16);
  m = (ushort_t)(tm >> 16);
  l = (ushort_t)(__float_as_uint(r2) >> 16);
}

// ---------------- k0: fold LN2 affine into W3 ----------------
__global__ __launch_bounds__(128) void k0_fold(
    const float* __restrict__ g2, const float* __restrict__ bt2,
    const float* __restrict__ W3, const float* __restrict__ b3,
    float* __restrict__ w3g, float* __restrict__ d2c3) {
  __shared__ double red[256];
  int f = threadIdx.x;
  w3g[f] = g2[f] * W3[f];
  red[f]       = (double)g2[f]  * (double)W3[f];
  red[128 + f] = (double)bt2[f] * (double)W3[f];
  __syncthreads();
  if (f == 0) {
    double d2 = 0.0, c3 = 0.0;
    for (int i = 0; i < 128; ++i) { d2 += red[i]; c3 += red[128 + i]; }
    d2c3[0] = (float)d2;
    d2c3[1] = (float)(c3 + (double)b3[0]);
  }
}

// ---------------- k0b: pre-split W2 into packed lane-order B-fragments ----
// Bpk[p][nc][s][l][i] bf16, p=plane(h/m/l), nc=N-strip(4), s=kstep(8),
// l=lane(64), i=reg(8). Element = split_p(W2[k][col]),
// k = s*16 + (l>>5)*8 + i, col = nc*32 + (l&31).
__global__ __launch_bounds__(256) void k0b_split(
    const float* __restrict__ W2, ushort_t* __restrict__ Bpk) {
  int t = blockIdx.x * 256 + threadIdx.x;    // 0..16383
  int k = t >> 7, col = t & 127;
  float x = W2[k * 128 + col];
  ushort_t h, m, l;
  split3(x, h, m, l);
  int nc = col >> 5;
  int ln = (col & 31) + ((k >> 3) & 1) * 32;
  int s  = k >> 4;
  int i  = k & 7;
  int base = ((nc * 8 + s) * 64 + ln) * 8 + i;
  Bpk[base]             = h;
  Bpk[16384 + base]     = m;
  Bpk[2 * 16384 + base] = l;
}

// ---------------- k1: P = nodes@W1[:128], Q = nodes@W1[128:] ----------------
__global__ __launch_bounds__(128) void k1_pq(
    const float* __restrict__ nodes, const float* __restrict__ W1,
    float* __restrict__ P, float* __restrict__ Q) {
  __shared__ float x[128];
  int row = blockIdx.x;
  int f = threadIdx.x;
  x[f] = nodes[row * 128 + f];
  __syncthreads();
  float p = 0.f, q = 0.f;
#pragma unroll 4
  for (int k = 0; k < 128; ++k) {
    float xk = x[k];
    p += xk * W1[k * 128 + f];
    q += xk * W1[(128 + k) * 128 + f];
  }
  P[row * 128 + f] = p;
  Q[row * 128 + f] = q;
}

// ---------------- k2: fused edge MLP (MFMA bf16x3) -> logits ----------------
// 4596 blocks x 4 tiles of 32 edges, 256 threads (4 waves). Wave w = strip w.
// Register plan fits the allocator's ~84-reg target: A dbuf 24 + B dist-1
// dbuf 24 + acc 16 (AGPR) + addr ~15. B re-read from L2 per k-step (opaque
// ptr per tile stops LICM). Separate sred buffer -> 2 barriers per tile.
__global__ __launch_bounds__(256) void k2_edges(
    const float* __restrict__ P, const float* __restrict__ Q,
    const float* __restrict__ b1, const float* __restrict__ g1,
    const float* __restrict__ bt1, const ushort_t* __restrict__ Bpk,
    const float* __restrict__ b2, const float* __restrict__ w3g,
    const float* __restrict__ d2c3, float* __restrict__ logits) {
  __shared__ __align__(16) unsigned char sPlanes[3 * 8192];  // h planes (24 KB)
  __shared__ float sred[BLK_E * 97];                         // 12.4 KB, separate
  __shared__ unsigned smeta[2][BLK_E];                       // double-buffered

  const int tid = threadIdx.x;
  const int w  = tid >> 6;           // wave 0..3 = N-strip
  const int l  = tid & 63;
  const unsigned lrow = (unsigned)(l & 31);
  const unsigned lk   = (unsigned)(l >> 5);
  const unsigned rb   = lrow * 256u;
  const unsigned esw  = lrow & 7u;
  const unsigned char* pl0 = sPlanes;
  const unsigned char* bp0 = (const unsigned char*)Bpk + (unsigned)(w * 8) * 1024u
                             + (unsigned)l * 16u;

  // epilogue constants (loop-invariant)
  const int col = w * 32 + (int)lrow;
  const float b2c = b2[col];
  const float w3c = w3g[col];
  const float dd2 = d2c3[0], cc3 = d2c3[1];

  bf16x8 A0h, A0m, A0l, A1h, A1m, A1l;
  bf16x8 B0h, B0m, B0l, B1h, B1m, B1l;

#define LOADA(S, ks) do {                                                     \
    const unsigned _co = (((unsigned)(2 * (ks)) + lk) ^ esw) << 4;            \
    A##S##h = *(const bf16x8*)(pl0 + rb + _co);                               \
    A##S##m = *(const bf16x8*)(pl0 + 8192 + rb + _co);                        \
    A##S##l = *(const bf16x8*)(pl0 + 2 * 8192 + rb + _co);                    \
  } while (0)

#define LOADB(S, ks) do {                                                     \
    B##S##h = *(const bf16x8*)(bpt + (ks) * 1024u);                           \
    B##S##m = *(const bf16x8*)(bpt + 32768u + (ks) * 1024u);                  \
    B##S##l = *(const bf16x8*)(bpt + 65536u + (ks) * 1024u);                  \
  } while (0)

#define MFMA6(AS, BS) do {                                                    \
    __builtin_amdgcn_s_setprio(1);                                            \
    acc = __builtin_amdgcn_mfma_f32_32x32x16_bf16(A##AS##m, B##BS##m, acc, 0, 0, 0); \
    acc = __builtin_amdgcn_mfma_f32_32x32x16_bf16(A##AS##l, B##BS##h, acc, 0, 0, 0); \
    acc = __builtin_amdgcn_mfma_f32_32x32x16_bf16(A##AS##h, B##BS##l, acc, 0, 0, 0); \
    acc = __builtin_amdgcn_mfma_f32_32x32x16_bf16(A##AS##m, B##BS##h, acc, 0, 0, 0); \
    acc = __builtin_amdgcn_mfma_f32_32x32x16_bf16(A##AS##h, B##BS##m, acc, 0, 0, 0); \
    acc = __builtin_amdgcn_mfma_f32_32x32x16_bf16(A##AS##h, B##BS##h, acc, 0, 0, 0); \
    __builtin_amdgcn_s_setprio(0);                                            \
    __builtin_amdgcn_sched_barrier(0);                                        \
  } while (0)

  for (int it = 0; it < TILES_PER_BLK; ++it) {
    const int tile = blockIdx.x * TILES_PER_BLK + it;

    // =============== phase A: h1 = LN1(relu(P[si]+Q[so]+b1)) ================
    {
      const int e = tid >> 3;        // edge 0..31
      const int q = tid & 7;         // 16-elem chunk
      int g = tile * BLK_E + e;
      int b = g / E_PER_B;
      int t0 = g - b * E_PER_B;
      int si = (int)((1.0 + sqrt(1.0 + 8.0 * (double)t0)) * 0.5);
      while (si * (si - 1) / 2 > t0) --si;
      while ((si + 1) * si / 2 <= t0) ++si;
      int so = t0 - si * (si - 1) / 2;
      if (q == 0) smeta[it & 1][e] = (unsigned)((b * NN + si) * (NN - 1) + so);

      const float4* P4  = (const float4*)(P + (size_t)(b * NN + si) * 128) + q * 4;
      const float4* Q4  = (const float4*)(Q + (size_t)(b * NN + so) * 128) + q * 4;
      const float4* B14 = (const float4*)b1 + q * 4;
      float av[16];
      float sum = 0.f;
#pragma unroll
      for (int k4 = 0; k4 < 4; ++k4) {
        float4 p = P4[k4], qq = Q4[k4], bb = B14[k4];
        float v0 = fmaxf(p.x + qq.x + bb.x, 0.f);
        float v1 = fmaxf(p.y + qq.y + bb.y, 0.f);
        float v2 = fmaxf(p.z + qq.z + bb.z, 0.f);
        float v3 = fmaxf(p.w + qq.w + bb.w, 0.f);
        av[4 * k4 + 0] = v0; av[4 * k4 + 1] = v1;
        av[4 * k4 + 2] = v2; av[4 * k4 + 3] = v3;
        sum += v0 + v1 + v2 + v3;
      }
      sum += __shfl_xor(sum, 1);
      sum += __shfl_xor(sum, 2);
      sum += __shfl_xor(sum, 4);
      float m = sum * 0.0078125f;
      float ss = 0.f;
#pragma unroll
      for (int j = 0; j < 16; ++j) { float dx = av[j] - m; ss += dx * dx; }
      ss += __shfl_xor(ss, 1);
      ss += __shfl_xor(ss, 2);
      ss += __shfl_xor(ss, 4);
      float var = ss * 0.0078125f;
      float rs = 1.0f / sqrtf(var + 1e-5f);

      const float4* G14  = (const float4*)g1 + q * 4;
      const float4* BT14 = (const float4*)bt1 + q * 4;
#pragma unroll
      for (int k4 = 0; k4 < 4; ++k4) {
        float4 gg = G14[k4], bt = BT14[k4];
        av[4 * k4 + 0] = (av[4 * k4 + 0] - m) * rs * gg.x + bt.x;
        av[4 * k4 + 1] = (av[4 * k4 + 1] - m) * rs * gg.y + bt.y;
        av[4 * k4 + 2] = (av[4 * k4 + 2] - m) * rs * gg.z + bt.z;
        av[4 * k4 + 3] = (av[4 * k4 + 3] - m) * rs * gg.w + bt.w;
      }
      const unsigned esw0 = (unsigned)(e & 7);
#pragma unroll
      for (int j = 0; j < 2; ++j) {
        unsigned ph[4], pm[4], pl[4];
#pragma unroll
        for (int ii = 0; ii < 4; ++ii) {
          ushort_t h0, m0, l0, h1x, m1x, l1x;
          split3(av[j * 8 + 2 * ii],     h0, m0, l0);
          split3(av[j * 8 + 2 * ii + 1], h1x, m1x, l1x);
          ph[ii] = (unsigned)h0 | ((unsigned)h1x << 16);
          pm[ii] = (unsigned)m0 | ((unsigned)m1x << 16);
          pl[ii] = (unsigned)l0 | ((unsigned)l1x << 16);
        }
        unsigned slot = (unsigned)(2 * q + j) ^ esw0;
        unsigned base = (unsigned)e * 256u + (slot << 4);
        *(uint4*)(sPlanes + base)             = make_uint4(ph[0], ph[1], ph[2], ph[3]);
        *(uint4*)(sPlanes + 8192 + base)      = make_uint4(pm[0], pm[1], pm[2], pm[3]);
        *(uint4*)(sPlanes + 2 * 8192 + base)  = make_uint4(pl[0], pl[1], pl[2], pl[3]);
      }
    }

    // B k-step 0 into slot 0 (issued before the barrier; opaque ptr per tile
    // prevents LICM from hoisting the whole B set out of the tile loop).
    const unsigned char* bpt = bp0;
    asm volatile("" : "+v"(bpt));
    LOADB(0, 0);

    __syncthreads();   // bar1: planes ready

    // ===== GEMM: h1[32x128] @ W2strip[128x32], 6-product bf16 ==============
    f32x16 acc;
#pragma unroll
    for (int i = 0; i < 16; ++i) acc[i] = 0.f;

    LOADA(0, 0);
    LOADB(1, 1); LOADA(1, 1); MFMA6(0, 0);
    LOADB(0, 2); LOADA(0, 2); MFMA6(1, 1);
    LOADB(1, 3); LOADA(1, 3); MFMA6(0, 0);
    LOADB(0, 4); LOADA(0, 4); MFMA6(1, 1);
    LOADB(1, 5); LOADA(1, 5); MFMA6(0, 0);
    LOADB(0, 6); LOADA(0, 6); MFMA6(1, 1);
    LOADB(1, 7); LOADA(1, 7); MFMA6(0, 0);
    MFMA6(1, 1);

    // =============== epilogue: per-edge stats partials -> sred ==============
    {
      const unsigned ebase = 4u * lk;
#pragma unroll
      for (int r = 0; r < 16; ++r) {
        float a = acc[r];
        float rr = fmaxf(a + b2c, 0.f);
        float s_ = rr, q_ = rr * rr, d_ = rr * w3c;
        s_ += __shfl_xor(s_, 1); s_ += __shfl_xor(s_, 2);
        q_ += __shfl_xor(q_, 1); q_ += __shfl_xor(q_, 2);
        d_ += __shfl_xor(d_, 1); d_ += __shfl_xor(d_, 2);
        if ((l & 3) == 0) {
          unsigned e = ebase + (unsigned)((r & 3) + 8 * (r >> 2));
          unsigned idx = e * 97u + (unsigned)(w * 8 + (int)(lrow >> 2)) * 3u;
          sred[idx]     = s_;
          sred[idx + 1] = q_;
          sred[idx + 2] = d_;
        }
      }
    }
    __syncthreads();   // bar2: sred ready; planes free for next tile

    // =============== pass 2: LN2-fold + W3 -> logit =========================
    if (tid < BLK_E) {
      const float* rp = sred + tid * 97;
      float s = 0.f, q = 0.f, d = 0.f;
#pragma unroll
      for (int j = 0; j < 32; ++j) {
        s += rp[3 * j];
        q += rp[3 * j + 1];
        d += rp[3 * j + 2];
      }
      float m2 = s * 0.0078125f;
      float var = fmaxf(q * 0.0078125f - m2 * m2, 0.f);
      float rs2 = 1.0f / sqrtf(var + 1e-5f);
      logits[smeta[it & 1][tid]] = rs2 * d - m2 * rs2 * dd2 + cc3;
    }
    // no barrier: next phase A writes planes (all reads done before bar2);
    // smeta is double-buffered; next sred write is after next bar1.
  }
#undef LOADA
#undef LOADB
#undef MFMA6
}

// ---------------- kz: zero output ----------------
__global__ __launch_bounds__(256) void kz_zero(float4* __restrict__ out, int n4) {
  int i = blockIdx.x * 256 + threadIdx.x;
  if (i < n4) out[i] = make_float4(0.f, 0.f, 0.f, 0.f);
}

// ---------------- k3: per (b,i,sample) gumbel argmax -> out=1 ----------------
__global__ __launch_bounds__(320) void k3_argmax(
    const float* __restrict__ logits, float* __restrict__ out) {
  int blk = blockIdx.x;
  int b = blk / NN;
  int i = blk - b * NN;
  if (i == 0) return;                    // row 0's pick lands on the diagonal
  int s = threadIdx.x >> 6;              // sample 0..4 (one wave each)
  int lane = threadIdx.x & 63;
  const float* row = logits + (size_t)(b * NN + i) * (NN - 1);
  float best = -INFINITY;
  int bestj = 0x7fffffff;
  unsigned lbase = ((unsigned)((s * NB + b) * NN + i)) * (NN - 1);
  for (int j = lane; j < i; j += 64) {
    float v = row[j] + gumbel_noise(lbase + (unsigned)j);
    if (v > best) { best = v; bestj = j; }
  }
  for (int off = 32; off; off >>= 1) {
    float ov = __shfl_down(best, off);
    int oj = __shfl_down(bestj, off);
    if (ov > best || (ov == best && oj < bestj)) { best = ov; bestj = oj; }
  }
  if (lane == 0) out[((size_t)(b * NN) + i) * NN + bestj] = 1.0f;
}

// ---------------- launch ----------------
extern "C" void kernel_launch(void* const* d_in, const int* in_sizes, int n_in,
                              void* d_out, int out_size, void* d_ws, size_t ws_size,
                              hipStream_t stream) {
  const float* nodes = (const float*)d_in[0];
  const float* W1  = (const float*)d_in[1];
  const float* b1  = (const float*)d_in[2];
  const float* g1  = (const float*)d_in[3];
  const float* bt1 = (const float*)d_in[4];
  const float* W2  = (const float*)d_in[5];
  const float* b2  = (const float*)d_in[6];
  const float* g2  = (const float*)d_in[7];
  const float* bt2 = (const float*)d_in[8];
  const float* W3  = (const float*)d_in[9];
  const float* b3  = (const float*)d_in[10];

  float* ws     = (float*)d_ws;
  float* Pw     = ws;                 // 393216 floats
  float* Qw     = ws + 393216;        // 393216
  float* w3g    = ws + 786432;        // 128
  float* d2c3   = ws + 786560;        // 2
  float* logits = ws + 786688;        // 1176576
  ushort_t* Bpk = (ushort_t*)(ws + 1963264);  // 49152 bf16 = 96 KB

  hipLaunchKernelGGL(k0_fold, dim3(1), dim3(128), 0, stream, g2, bt2, W3, b3, w3g, d2c3);
  hipLaunchKernelGGL(k0b_split, dim3(64), dim3(256), 0, stream, W2, Bpk);
  hipLaunchKernelGGL(k1_pq, dim3(NB * NN), dim3(128), 0, stream, nodes, W1, Pw, Qw);
  hipLaunchKernelGGL(k2_edges, dim3(K2_GRID), dim3(256), 0, stream,
                     Pw, Qw, b1, g1, bt1, Bpk, b2, w3g, d2c3, logits);
  int n4 = out_size / 4;              // 294912
  hipLaunchKernelGGL(kz_zero, dim3((n4 + 255) / 256), dim3(256), 0, stream,
                     (float4*)d_out, n4);
  hipLaunchKernelGGL(k3_argmax, dim3(NB * NN), dim3(320), 0, stream, logits, (float*)d_out);
}